// Round 6
// baseline (396.956 us; speedup 1.0000x reference)
//
#include <hip/hip_runtime.h>
#include <math.h>

constexpr int N = 20000, D = 256, E = 320000, B = 2, L = 2;

typedef __bf16 bf16x8 __attribute__((ext_vector_type(8)));
typedef float f32x4 __attribute__((ext_vector_type(4)));

__device__ __forceinline__ unsigned short f2bf(float f) {
  unsigned int u = __float_as_uint(f);
  u = (u + 0x7FFF + ((u >> 16) & 1)) >> 16;  // RNE
  return (unsigned short)u;
}
__device__ __forceinline__ float bfhi(unsigned int u) { return __uint_as_float(u & 0xFFFF0000u); }
__device__ __forceinline__ float bflo(unsigned int u) { return __uint_as_float(u << 16); }

// ---------------- CSR build (both batches) ----------------
__global__ void count_kernel(const int* __restrict__ edges, int* __restrict__ counts) {
  int e = blockIdx.x * blockDim.x + threadIdx.x;
  if (e < B * E) {
    int b = (e >= E) ? 1 : 0;
    int s = edges[(size_t)b * E + e];
    atomicAdd(&counts[b * N + s], 1);
  }
}

__global__ __launch_bounds__(1024) void scan_kernel(const int* __restrict__ counts,
                                                    int* __restrict__ rowstart) {
  constexpr int CHUNK = 20;
  __shared__ int sums[1024];
  int b = blockIdx.x;
  const int* c = counts + b * N;
  int* rs = rowstart + b * (N + 1);
  int tid = threadIdx.x;
  int base = tid * CHUNK;
  int local[CHUNK];
  int s = 0;
#pragma unroll
  for (int i = 0; i < CHUNK; ++i) {
    int g = base + i;
    int v = (g < N) ? c[g] : 0;
    local[i] = s;
    s += v;
  }
  sums[tid] = s;
  __syncthreads();
  for (int off = 1; off < 1024; off <<= 1) {
    int t = (tid >= off) ? sums[tid - off] : 0;
    __syncthreads();
    sums[tid] += t;
    __syncthreads();
  }
  int prev = (tid == 0) ? 0 : sums[tid - 1];
#pragma unroll
  for (int i = 0; i < CHUNK; ++i) {
    int g = base + i;
    if (g < N) rs[g] = prev + local[i];
  }
  if (tid == 1023) rs[N] = sums[1023];
}

__global__ void scatter_kernel(const int* __restrict__ edges, const int* __restrict__ rowstart,
                               int* __restrict__ fill, int* __restrict__ csr) {
  int e = blockIdx.x * blockDim.x + threadIdx.x;
  if (e < B * E) {
    int b = (e >= E) ? 1 : 0;
    int s = edges[(size_t)b * E + e];
    int d = edges[(size_t)(b + 1) * E + e];
    int p = rowstart[b * (N + 1) + s] + atomicAdd(&fill[b * N + s], 1);
    csr[(size_t)b * E + p] = d;
  }
}

// ---------------- W transpose + bf16: Wt[l][n][k] = bf16(W[l][k][n]) ----------------
__global__ void wt_kernel(const float* __restrict__ W, unsigned short* __restrict__ Wt) {
  __shared__ float t[16][17];
  int l = blockIdx.z;
  int k = blockIdx.y * 16 + threadIdx.y;
  int n = blockIdx.x * 16 + threadIdx.x;
  t[threadIdx.y][threadIdx.x] = W[l * 65536 + k * 256 + n];
  __syncthreads();
  int nn = blockIdx.x * 16 + threadIdx.y;
  int kk = blockIdx.y * 16 + threadIdx.x;
  Wt[l * 65536 + nn * 256 + kk] = f2bf(t[threadIdx.x][threadIdx.y]);
}

// ---------------- wa[l] = W_l @ a_l[:D] ----------------
__global__ void wa_kernel(const float* __restrict__ W, const float* __restrict__ a,
                          float* __restrict__ wa) {
  int l = blockIdx.x;
  int k = threadIdx.x;
  float s = 0.f;
  for (int d = 0; d < D; ++d) s += W[l * 65536 + k * D + d] * a[l * 2 * D + d];
  wa[l * D + k] = s;
}

// ---------------- sq[(b*2+l)][n] = xq[b][n,:]·wa[l] ----------------
__global__ void sq_kernel(const float* __restrict__ xq, const float* __restrict__ wa,
                          float* __restrict__ sq) {
  int wave = (blockIdx.x * blockDim.x + threadIdx.x) >> 6;
  int lane = threadIdx.x & 63;
  int b = blockIdx.y;
  if (wave >= N) return;
  const float4 xv = *(const float4*)(xq + ((size_t)b * N + wave) * D + (lane << 2));
  const float4 w0 = *(const float4*)(wa + (lane << 2));
  const float4 w1 = *(const float4*)(wa + D + (lane << 2));
  float s0 = xv.x * w0.x + xv.y * w0.y + xv.z * w0.z + xv.w * w0.w;
  float s1 = xv.x * w1.x + xv.y * w1.y + xv.z * w1.z + xv.w * w1.w;
  for (int off = 32; off; off >>= 1) {
    s0 += __shfl_down(s0, off);
    s1 += __shfl_down(s1, off);
  }
  if (lane == 0) {
    sq[(b * 2 + 0) * N + wave] = s0;
    sq[(b * 2 + 1) * N + wave] = s1;
  }
}

// ---------------- MFMA GEMM (both batches): Cbf = A @ W, fused sn ----------------
// AF32: A is fp32 (convert in staging); else A is bf16.
template <bool AF32>
__global__ __launch_bounds__(256) void gemm_mfma(const void* __restrict__ Avoid,
                                                 const unsigned short* __restrict__ Wt,
                                                 unsigned short* __restrict__ Cbf,
                                                 const float* __restrict__ a2,
                                                 float* __restrict__ sn, int M) {
  __shared__ unsigned short As[128 * 32];  // [m][k]
  __shared__ unsigned short Bs[64 * 32];   // [n][k]
  int z = blockIdx.z;
  unsigned short* Cz = Cbf + (size_t)z * M * 256;
  float* snz = sn + (size_t)z * M;
  int tid = threadIdx.x;
  int bm = blockIdx.y * 128, bn = blockIdx.x * 64;
  int wv = tid >> 6, lane = tid & 63;
  int lm = lane & 15, lq = lane >> 4;
  f32x4 acc[2][4] = {};

  for (int k0 = 0; k0 < 256; k0 += 32) {
    int m = tid >> 1, kb = (tid & 1) << 4;
    if (bm + m < M) {
      if (AF32) {
        const float* ap = (const float*)Avoid + ((size_t)z * M + bm + m) * 256 + k0 + kb;
        unsigned short tmp[16];
#pragma unroll
        for (int q = 0; q < 4; ++q) {
          float4 v = *(const float4*)(ap + q * 4);
          tmp[q * 4 + 0] = f2bf(v.x);
          tmp[q * 4 + 1] = f2bf(v.y);
          tmp[q * 4 + 2] = f2bf(v.z);
          tmp[q * 4 + 3] = f2bf(v.w);
        }
        *(uint4*)&As[m * 32 + kb] = ((const uint4*)tmp)[0];
        *(uint4*)&As[m * 32 + kb + 8] = ((const uint4*)tmp)[1];
      } else {
        const unsigned short* ap =
            (const unsigned short*)Avoid + ((size_t)z * M + bm + m) * 256 + k0 + kb;
        *(uint4*)&As[m * 32 + kb] = *(const uint4*)ap;
        *(uint4*)&As[m * 32 + kb + 8] = *(const uint4*)(ap + 8);
      }
    } else {
      uint4 z4 = make_uint4(0, 0, 0, 0);
      *(uint4*)&As[m * 32 + kb] = z4;
      *(uint4*)&As[m * 32 + kb + 8] = z4;
    }
    int nn = tid >> 2, kb2 = (tid & 3) << 3;
    *(uint4*)&Bs[nn * 32 + kb2] = *(const uint4*)(Wt + (size_t)(bn + nn) * 256 + k0 + kb2);
    __syncthreads();

    bf16x8 af0 = *(const bf16x8*)&As[(wv * 32 + lm) * 32 + lq * 8];
    bf16x8 af1 = *(const bf16x8*)&As[(wv * 32 + 16 + lm) * 32 + lq * 8];
#pragma unroll
    for (int nf = 0; nf < 4; ++nf) {
      bf16x8 bfr = *(const bf16x8*)&Bs[(nf * 16 + lm) * 32 + lq * 8];
      acc[0][nf] = __builtin_amdgcn_mfma_f32_16x16x32_bf16(af0, bfr, acc[0][nf], 0, 0, 0);
      acc[1][nf] = __builtin_amdgcn_mfma_f32_16x16x32_bf16(af1, bfr, acc[1][nf], 0, 0, 0);
    }
    __syncthreads();
  }

  float a2v[4];
#pragma unroll
  for (int nf = 0; nf < 4; ++nf) a2v[nf] = a2[bn + nf * 16 + lm];
#pragma unroll
  for (int f = 0; f < 2; ++f) {
#pragma unroll
    for (int r = 0; r < 4; ++r) {
      int row = bm + wv * 32 + f * 16 + lq * 4 + r;
      if (row < M) {
        float partial = 0.f;
#pragma unroll
        for (int nf = 0; nf < 4; ++nf) {
          float v = acc[f][nf][r];
          Cz[(size_t)row * 256 + bn + nf * 16 + lm] = f2bf(v);
          partial += v * a2v[nf];
        }
        partial += __shfl_xor(partial, 1);
        partial += __shfl_xor(partial, 2);
        partial += __shfl_xor(partial, 4);
        partial += __shfl_xor(partial, 8);
        if (lm == 0) atomicAdd(&snz[row], partial);
      }
    }
  }
}

// ---------------- fused weight + aggregation: one block per node ----------------
// Phase 1: all 256 threads compute (idx,w) for up to 256 edges -> LDS (no redundancy).
// Phase 2: wave wv, lane-half eg process edge j = wv*2+eg (+8): (idx,w) via one
// broadcast ds_read_b64; 32 lanes x uint4 = 512B row gather; 8 fma.
__global__ __launch_bounds__(256) void agg_kernel(const int* __restrict__ rowstart,
                                                  const int* __restrict__ csr,
                                                  const float* __restrict__ sq_all,
                                                  const float* __restrict__ sn,
                                                  const unsigned short* __restrict__ hbf,
                                                  const float* __restrict__ resid,
                                                  float* __restrict__ outf,
                                                  unsigned short* __restrict__ outbf, int l) {
  __shared__ uint2 ew[256];
  __shared__ float part[4][8][32];
  __shared__ float prow[4];
  int node = blockIdx.x, b = blockIdx.y;
  int tid = threadIdx.x, wv = tid >> 6, lane = tid & 63;
  int eg = lane >> 5, dl = lane & 31;
  const int* rs = rowstart + b * (N + 1);
  const int* cs = csr + (size_t)b * E;
  const float* snb = sn + (size_t)b * N;
  const unsigned short* hb = hbf + (size_t)b * N * 256;
  int beg = rs[node], end = rs[node + 1];
  float sqv = sq_all[((b << 1) + l) * N + node];
  float wsum = 0.f;
  float acc[8] = {};
  for (int c0 = beg; c0 < end; c0 += 256) {
    int cnt = min(end - c0, 256);
    if (tid < cnt) {
      int idx = cs[c0 + tid];
      float s = sqv + snb[idx];
      float lr = (s >= 0.f) ? s : 0.2f * s;
      ew[tid] = make_uint2((unsigned)idx, __float_as_uint(__expf(-lr)));
    }
    __syncthreads();
#pragma unroll 4
    for (int j = wv * 2 + eg; j < cnt; j += 8) {
      uint2 p = ew[j];  // half-wave-uniform -> 2-addr broadcast, conflict-free
      float wj = __uint_as_float(p.y);
      wsum += wj;
      uint4 hv = *(const uint4*)(hb + (size_t)p.x * 256 + (dl << 3));
      acc[0] = fmaf(wj, bflo(hv.x), acc[0]);
      acc[1] = fmaf(wj, bfhi(hv.x), acc[1]);
      acc[2] = fmaf(wj, bflo(hv.y), acc[2]);
      acc[3] = fmaf(wj, bfhi(hv.y), acc[3]);
      acc[4] = fmaf(wj, bflo(hv.z), acc[4]);
      acc[5] = fmaf(wj, bfhi(hv.z), acc[5]);
      acc[6] = fmaf(wj, bflo(hv.w), acc[6]);
      acc[7] = fmaf(wj, bfhi(hv.w), acc[7]);
    }
    __syncthreads();
  }
  // merge lane halves (each edge was processed by exactly one half)
#pragma unroll
  for (int i = 0; i < 8; ++i) acc[i] += __shfl_xor(acc[i], 32);
  wsum += __shfl_xor(wsum, 32);
  if (lane == 0) prow[wv] = wsum;
  if (eg == 0) {
#pragma unroll
    for (int i = 0; i < 8; ++i) part[wv][i][dl] = acc[i];
  }
  __syncthreads();
  if (wv == 0) {
    float rsum = prow[0] + prow[1] + prow[2] + prow[3];
    float inv = (rsum > 0.f) ? 1.f / rsum : 0.f;
    int r = lane >> 1, c4 = (lane & 1) << 2;
    float4 o;
    o.x = (part[0][c4 + 0][r] + part[1][c4 + 0][r] + part[2][c4 + 0][r] + part[3][c4 + 0][r]) * inv;
    o.y = (part[0][c4 + 1][r] + part[1][c4 + 1][r] + part[2][c4 + 1][r] + part[3][c4 + 1][r]) * inv;
    o.z = (part[0][c4 + 2][r] + part[1][c4 + 2][r] + part[2][c4 + 2][r] + part[3][c4 + 2][r]) * inv;
    o.w = (part[0][c4 + 3][r] + part[1][c4 + 3][r] + part[2][c4 + 3][r] + part[3][c4 + 3][r]) * inv;
    size_t rowoff = ((size_t)b * N + node) * 256 + (lane << 2);
    if (outbf) {
      unsigned short t[4] = {f2bf(o.x), f2bf(o.y), f2bf(o.z), f2bf(o.w)};
      *(uint2*)(outbf + rowoff) = *(uint2*)t;
    } else {
      const float4 rv = *(const float4*)(resid + rowoff);
      o.x += rv.x;
      o.y += rv.y;
      o.z += rv.z;
      o.w += rv.w;
      *(float4*)(outf + rowoff) = o;
    }
  }
}

extern "C" void kernel_launch(void* const* d_in, const int* in_sizes, int n_in,
                              void* d_out, int out_size, void* d_ws, size_t ws_size,
                              hipStream_t stream) {
  const float* nodes = (const float*)d_in[0];
  const float* nodesq = (const float*)d_in[1];
  const float* W = (const float*)d_in[2];
  const float* a = (const float*)d_in[3];
  const int* edges = (const int*)d_in[4];
  float* out = (float*)d_out;

  const size_t ND = (size_t)N * D;
  unsigned short* hbf = (unsigned short*)d_ws;  // B*N*D  (GEMM output h_proj)
  unsigned short* h1bf = hbf + (size_t)B * ND;  // B*N*D  (layer-0 agg output)
  unsigned short* Wt = h1bf + (size_t)B * ND;   // L*D*D
  float* ws_f = (float*)(Wt + (size_t)L * D * D);
  float* sn = ws_f;                        // B*N
  float* sq_all = sn + B * N;              // B*L*N
  float* wa = sq_all + (size_t)B * L * N;  // L*D
  int* wsi = (int*)(wa + L * D);
  int* counts = wsi;                  // B*N
  int* fill = counts + B * N;         // B*N
  int* rowstart = fill + B * N;       // B*(N+1)
  int* csr = rowstart + B * (N + 1);  // B*E

  wt_kernel<<<dim3(16, 16, 2), dim3(16, 16), 0, stream>>>(W, Wt);
  wa_kernel<<<2, 256, 0, stream>>>(W, a, wa);

  hipMemsetAsync(counts, 0, (size_t)2 * B * N * sizeof(int), stream);
  count_kernel<<<(B * E + 255) / 256, 256, 0, stream>>>(edges, counts);
  scan_kernel<<<B, 1024, 0, stream>>>(counts, rowstart);
  scatter_kernel<<<(B * E + 255) / 256, 256, 0, stream>>>(edges, rowstart, fill, csr);

  int nwave_blocks = (N * 64 + 255) / 256;
  sq_kernel<<<dim3(nwave_blocks, B), 256, 0, stream>>>(nodesq, wa, sq_all);

  for (int l = 0; l < L; ++l) {
    const float* al2 = a + (size_t)l * 2 * D + D;
    hipMemsetAsync(sn, 0, (size_t)B * N * sizeof(float), stream);
    if (l == 0)
      gemm_mfma<true><<<dim3(4, (N + 127) / 128, B), 256, 0, stream>>>(nodes, Wt, hbf, al2, sn, N);
    else
      gemm_mfma<false><<<dim3(4, (N + 127) / 128, B), 256, 0, stream>>>(
          h1bf, Wt + (size_t)D * D, hbf, al2, sn, N);
    bool last = (l == L - 1);
    agg_kernel<<<dim3(N, B), 256, 0, stream>>>(rowstart, csr, sq_all, sn, hbf,
                                               last ? nodes : nullptr, last ? out : nullptr,
                                               last ? nullptr : h1bf, l);
  }
}